// Round 1
// baseline (716.904 us; speedup 1.0000x reference)
//
#include <hip/hip_runtime.h>
#include <hip/hip_bf16.h>
#include <stdint.h>

#define M_DIM 8192
#define N_DIM 4096
#define K_DIM 4096

typedef __bf16 bf16x8 __attribute__((ext_vector_type(8)));
typedef float f32x4 __attribute__((ext_vector_type(4)));

// ---------------------------------------------------------------- helpers
__device__ __forceinline__ unsigned short f2bf(float f) {
  // round-to-nearest-even fp32 -> bf16 (no NaN inputs in this problem)
  unsigned int u = __float_as_uint(f);
  u += 0x7fffu + ((u >> 16) & 1u);
  return (unsigned short)(u >> 16);
}

__device__ __forceinline__ unsigned int pack2(float lo, float hi) {
  return (unsigned int)f2bf(lo) | ((unsigned int)f2bf(hi) << 16);
}

// async global->LDS, 16 B per lane. LDS dest is wave-uniform base + lane*16.
__device__ __forceinline__ void async_copy16(const void* g, void* l) {
  __builtin_amdgcn_global_load_lds(
      (__attribute__((address_space(1))) void*)(g),
      (__attribute__((address_space(3))) void*)(l),
      16, 0, 0);
}

// ------------------------------------------------ prepass 1: A fp32->bf16
// one thread = 8 elements: 2x float4 load (32 B), 1x uint4 store (16 B)
__global__ void convert_a_kernel(const float* __restrict__ in,
                                 unsigned short* __restrict__ out) {
  size_t t = (size_t)blockIdx.x * 256 + threadIdx.x;
  size_t base = t * 8;
  const float4* p = (const float4*)(in + base);
  float4 v0 = p[0], v1 = p[1];
  uint4 o;
  o.x = pack2(v0.x, v0.y);
  o.y = pack2(v0.z, v0.w);
  o.z = pack2(v1.x, v1.y);
  o.w = pack2(v1.z, v1.w);
  *(uint4*)(out + base) = o;
}

// --------------------------- prepass 2: Wt[o][i] = bf16(W[i][o]*Mask[i][o])
// 32x32 tile transpose through LDS (stride 33 -> conflict-free)
__global__ void maskT_kernel(const float* __restrict__ W,
                             const float* __restrict__ Msk,
                             unsigned short* __restrict__ Wt) {
  __shared__ float tile[32][33];
  const int tx = threadIdx.x, ty = threadIdx.y;
  const size_t i0 = (size_t)blockIdx.y * 32;
  const size_t o0 = (size_t)blockIdx.x * 32;
  const size_t gi = (i0 + ty) * N_DIM + o0 + tx;
  tile[ty][tx] = W[gi] * Msk[gi];
  __syncthreads();
  Wt[(o0 + ty) * K_DIM + i0 + tx] = f2bf(tile[tx][ty]);
}

// ------------------------------------------------ main GEMM (m97 structure)
// A: bf16 [M][K] row-major; Bt: bf16 [N][K] row-major; C: fp32 [M][N]
// 128x128 block tile, BK=32, 256 threads = 4 waves in 2x2, each wave 64x64
__global__ __launch_bounds__(256) void gemm_bf16_kernel(
    const unsigned short* __restrict__ A,
    const unsigned short* __restrict__ Bt,
    float* __restrict__ C) {
  __shared__ unsigned short As[128 * 32];   // [row][k] contiguous in k
  __shared__ unsigned short Bs[128 * 32];   // [col][k] contiguous in k

  const int tid  = threadIdx.x;
  const int wave = tid >> 6;
  const int lane = tid & 63;
  const int l16  = lane & 15;
  const int quad = lane >> 4;
  const int wm   = (wave & 1) * 64;   // wave's M offset within tile
  const int wn   = (wave >> 1) * 64;  // wave's N offset within tile

  const size_t bm = (size_t)blockIdx.y * 128;
  const size_t bn = (size_t)blockIdx.x * 128;

  // staging: thread covers row r (and r+64), 8 bf16 k-segment
  const int r    = tid >> 2;
  const int kseg = (tid & 3) * 8;

  const unsigned short* ag0 = A  + (bm + r)      * K_DIM + kseg;
  const unsigned short* ag1 = A  + (bm + r + 64) * K_DIM + kseg;
  const unsigned short* bg0 = Bt + (bn + r)      * K_DIM + kseg;
  const unsigned short* bg1 = Bt + (bn + r + 64) * K_DIM + kseg;

  // wave-uniform LDS bases; HW adds lane*16 bytes
  unsigned short* al0 = As + wave * 512;
  unsigned short* al1 = As + 2048 + wave * 512;
  unsigned short* bl0 = Bs + wave * 512;
  unsigned short* bl1 = Bs + 2048 + wave * 512;

  f32x4 acc[4][4] = {};

  for (int k0 = 0; k0 < K_DIM; k0 += 32) {
    async_copy16(ag0, al0);
    async_copy16(ag1, al1);
    async_copy16(bg0, bl0);
    async_copy16(bg1, bl1);
    ag0 += 32; ag1 += 32; bg0 += 32; bg1 += 32;
    __syncthreads();  // drains vmcnt before barrier -> staging visible

    bf16x8 af[4], bfr[4];
#pragma unroll
    for (int mt = 0; mt < 4; ++mt)
      af[mt] = *(const bf16x8*)(As + (wm + mt * 16 + l16) * 32 + quad * 8);
#pragma unroll
    for (int nt = 0; nt < 4; ++nt)
      bfr[nt] = *(const bf16x8*)(Bs + (wn + nt * 16 + l16) * 32 + quad * 8);

#pragma unroll
    for (int mt = 0; mt < 4; ++mt)
#pragma unroll
      for (int nt = 0; nt < 4; ++nt)
        acc[mt][nt] = __builtin_amdgcn_mfma_f32_16x16x32_bf16(
            af[mt], bfr[nt], acc[mt][nt], 0, 0, 0);

    __syncthreads();  // protect LDS before next stage overwrites
  }

  // epilogue: C/D layout col=lane&15, row=quad*4+i  [verified m89/m91]
#pragma unroll
  for (int mt = 0; mt < 4; ++mt) {
    const size_t row0 = bm + wm + mt * 16 + quad * 4;
#pragma unroll
    for (int nt = 0; nt < 4; ++nt) {
      const size_t col = bn + wn + nt * 16 + l16;
      float* cp = C + row0 * N_DIM + col;
#pragma unroll
      for (int i = 0; i < 4; ++i)
        cp[(size_t)i * N_DIM] = acc[mt][nt][i];
    }
  }
}

// ------------------------------------------ fallback: fp32 tiled (insurance)
__global__ void gemm_f32_fallback(const float* __restrict__ A,
                                  const float* __restrict__ W,
                                  const float* __restrict__ Msk,
                                  float* __restrict__ C) {
  __shared__ float As[32][33];
  __shared__ float Bs[32][33];
  const int tx = threadIdx.x;  // 0..31 (n)
  const int ty = threadIdx.y;  // 0..7
  const size_t row0 = (size_t)blockIdx.y * 32;
  const size_t col0 = (size_t)blockIdx.x * 32;
  float acc[4] = {0.f, 0.f, 0.f, 0.f};
  for (int k0 = 0; k0 < K_DIM; k0 += 32) {
#pragma unroll
    for (int rr = 0; rr < 4; ++rr) {
      int rw = ty + rr * 8;
      As[rw][tx] = A[(row0 + rw) * K_DIM + k0 + tx];
      size_t gi = (size_t)(k0 + rw) * N_DIM + col0 + tx;
      Bs[rw][tx] = W[gi] * Msk[gi];
    }
    __syncthreads();
#pragma unroll
    for (int kk = 0; kk < 32; ++kk) {
      float b = Bs[kk][tx];
#pragma unroll
      for (int rr = 0; rr < 4; ++rr) acc[rr] += As[ty + rr * 8][kk] * b;
    }
    __syncthreads();
  }
#pragma unroll
  for (int rr = 0; rr < 4; ++rr)
    C[(row0 + ty + rr * 8) * N_DIM + col0 + tx] = acc[rr];
}

// ---------------------------------------------------------------- launcher
extern "C" void kernel_launch(void* const* d_in, const int* in_sizes, int n_in,
                              void* d_out, int out_size, void* d_ws,
                              size_t ws_size, hipStream_t stream) {
  const float* A   = (const float*)d_in[0];
  const float* W   = (const float*)d_in[1];
  const float* Msk = (const float*)d_in[2];
  float* C = (float*)d_out;

  const size_t bytesA = (size_t)M_DIM * K_DIM * sizeof(unsigned short);  // 64 MB
  const size_t bytesB = (size_t)K_DIM * N_DIM * sizeof(unsigned short);  // 32 MB

  if (ws_size >= bytesA + bytesB) {
    unsigned short* Abf = (unsigned short*)d_ws;
    unsigned short* Wt  = (unsigned short*)((char*)d_ws + bytesA);
    convert_a_kernel<<<dim3(((size_t)M_DIM * K_DIM) / 8 / 256), dim3(256), 0,
                       stream>>>(A, Abf);
    maskT_kernel<<<dim3(N_DIM / 32, K_DIM / 32), dim3(32, 32), 0, stream>>>(
        W, Msk, Wt);
    gemm_bf16_kernel<<<dim3(N_DIM / 128, M_DIM / 128), dim3(256), 0, stream>>>(
        Abf, Wt, C);
  } else {
    // workspace too small for bf16 staging: correct (slow) fp32 path
    gemm_f32_fallback<<<dim3(N_DIM / 32, M_DIM / 32), dim3(32, 8), 0,
                        stream>>>(A, W, Msk, C);
  }
}

// Round 2
// 716.575 us; speedup vs baseline: 1.0005x; 1.0005x over previous
//
#include <hip/hip_runtime.h>
#include <hip/hip_bf16.h>
#include <stdint.h>

#define M_DIM 8192
#define N_DIM 4096
#define K_DIM 4096

typedef __bf16 bf16x8 __attribute__((ext_vector_type(8)));
typedef float f32x4 __attribute__((ext_vector_type(4)));

// ---------------------------------------------------------------- helpers
__device__ __forceinline__ unsigned short f2bf(float f) {
  unsigned int u = __float_as_uint(f);
  u += 0x7fffu + ((u >> 16) & 1u);
  return (unsigned short)(u >> 16);
}
__device__ __forceinline__ unsigned int pack2(float lo, float hi) {
  return (unsigned int)f2bf(lo) | ((unsigned int)f2bf(hi) << 16);
}
__device__ __forceinline__ void async_copy16(const void* g, void* l) {
  __builtin_amdgcn_global_load_lds(
      (__attribute__((address_space(1))) void*)(g),
      (__attribute__((address_space(3))) void*)(l),
      16, 0, 0);
}

// ------------------------------------------------ prepass 1: A fp32->bf16
// 16 elems/thread: 4x float4 load (64 B), 2x uint4 store (32 B)
__global__ void convert_a_kernel(const float* __restrict__ in,
                                 unsigned short* __restrict__ out) {
  size_t t = (size_t)blockIdx.x * 256 + threadIdx.x;
  size_t base = t * 16;
  const float4* p = (const float4*)(in + base);
  float4 v0 = p[0], v1 = p[1], v2 = p[2], v3 = p[3];
  uint4 o0, o1;
  o0.x = pack2(v0.x, v0.y); o0.y = pack2(v0.z, v0.w);
  o0.z = pack2(v1.x, v1.y); o0.w = pack2(v1.z, v1.w);
  o1.x = pack2(v2.x, v2.y); o1.y = pack2(v2.z, v2.w);
  o1.z = pack2(v3.x, v3.y); o1.w = pack2(v3.z, v3.w);
  uint4* q = (uint4*)(out + base);
  q[0] = o0; q[1] = o1;
}

// --------------------------- prepass 2: Wt[o][i] = bf16(W[i][o]*Mask[i][o])
// 64x64 tile, 256 threads. Phase1: float4 loads, packed ds_write_b64 into
// transposed LDS tile (stride 72 shorts = 144 B, 16B-aligned rows).
// Phase2: ds_read_b128 x2 + 16 B global stores (conflict-free bank walk).
#define TS 72
__global__ __launch_bounds__(256) void maskT_kernel(
    const float* __restrict__ W, const float* __restrict__ Msk,
    unsigned short* __restrict__ Wt) {
  __shared__ unsigned short tile[64 * TS];
  const int t = threadIdx.x;
  const size_t i0 = (size_t)blockIdx.y * 64;
  const size_t o0 = (size_t)blockIdx.x * 64;

  const int o4 = (t & 15) * 4;   // col group (contiguous across lanes)
  const int i4 = (t >> 4) * 4;   // row group
  float4 w[4], m[4];
#pragma unroll
  for (int r = 0; r < 4; ++r) {
    const size_t gi = (i0 + i4 + r) * N_DIM + o0 + o4;
    w[r] = *(const float4*)(W + gi);
    m[r] = *(const float4*)(Msk + gi);
  }
  float e[4][4];
#pragma unroll
  for (int r = 0; r < 4; ++r) {
    e[r][0] = w[r].x * m[r].x; e[r][1] = w[r].y * m[r].y;
    e[r][2] = w[r].z * m[r].z; e[r][3] = w[r].w * m[r].w;
  }
#pragma unroll
  for (int c = 0; c < 4; ++c) {
    uint2 packed;
    packed.x = pack2(e[0][c], e[1][c]);
    packed.y = pack2(e[2][c], e[3][c]);
    *(uint2*)(tile + (o4 + c) * TS + i4) = packed;  // tile[o][i], 8 B store
  }
  __syncthreads();

  const int o_l = t >> 2;
  const int iseg = (t & 3) * 16;
  uint4 a = *(const uint4*)(tile + o_l * TS + iseg);
  uint4 b = *(const uint4*)(tile + o_l * TS + iseg + 8);
  unsigned short* dst = Wt + (o0 + o_l) * K_DIM + i0 + iseg;
  ((uint4*)dst)[0] = a;
  ((uint4*)dst)[1] = b;
}

// ------------------------------------------------ main GEMM (m97 structure)
// A: bf16 [M][K]; Bt: bf16 [N][K]; C: fp32 [M][N]
// 128x128 tile, BK=32, 4 waves, each 64x64 of 16x16x32 MFMA.
// LDS: [row][4 x 16B segs]; physical seg p holds global kseg q = p ^ ((row>>1)&3)
// -> every 8-lane ds_read_b128 phase covers 8 distinct bank quartets.
__global__ __launch_bounds__(256) void gemm_bf16_kernel(
    const unsigned short* __restrict__ A,
    const unsigned short* __restrict__ Bt,
    float* __restrict__ C) {
  __shared__ unsigned short As[128 * 32];
  __shared__ unsigned short Bs[128 * 32];

  const int tid  = threadIdx.x;
  const int wave = tid >> 6;
  const int lane = tid & 63;
  const int l16  = lane & 15;
  const int quad = lane >> 4;
  const int wm   = (wave & 1) * 64;
  const int wn   = (wave >> 1) * 64;

  // XCD-aware supertile: round-robin id%8 -> XCD. Give each XCD a 4(bx) x
  // 8(by) supertile per 256-block dispatch wave: B strip reused 8x, A 4x
  // from the XCD's own L2 instead of streaming from L3.
  const int flat  = blockIdx.y * 32 + blockIdx.x;
  const int dwave = flat >> 8;
  const int r8    = flat & 255;
  const int xcd   = r8 & 7;
  const int slot  = r8 >> 3;
  const int bx    = xcd * 4 + (slot & 3);
  const int by    = dwave * 8 + (slot >> 2);
  const size_t bm = (size_t)by * 128;
  const size_t bn = (size_t)bx * 128;

  // staging: thread covers row r (and r+64); physical 16B slot sp holds
  // global kseg q = sp ^ ((r>>1)&3)  (row+64 has same (row>>1)&3)
  const int r    = tid >> 2;
  const int sp   = tid & 3;
  const int kseg = (sp ^ ((r >> 1) & 3)) * 8;

  const unsigned short* ag0 = A  + (bm + r)      * K_DIM + kseg;
  const unsigned short* ag1 = A  + (bm + r + 64) * K_DIM + kseg;
  const unsigned short* bg0 = Bt + (bn + r)      * K_DIM + kseg;
  const unsigned short* bg1 = Bt + (bn + r + 64) * K_DIM + kseg;

  unsigned short* al0 = As + wave * 512;
  unsigned short* al1 = As + 2048 + wave * 512;
  unsigned short* bl0 = Bs + wave * 512;
  unsigned short* bl1 = Bs + 2048 + wave * 512;

  // reader: logical kseg = quad; physical seg = quad ^ ((row>>1)&3),
  // and (row>>1)&3 == (l16>>1)&3 for every fragment row (wm,mt*16 mults of 16)
  const int rseg = (quad ^ ((l16 >> 1) & 3)) * 8;

  f32x4 acc[4][4] = {};

  for (int k0 = 0; k0 < K_DIM; k0 += 32) {
    async_copy16(ag0, al0);
    async_copy16(ag1, al1);
    async_copy16(bg0, bl0);
    async_copy16(bg1, bl1);
    ag0 += 32; ag1 += 32; bg0 += 32; bg1 += 32;
    __syncthreads();

    bf16x8 af[4], bfr[4];
#pragma unroll
    for (int mt = 0; mt < 4; ++mt)
      af[mt] = *(const bf16x8*)(As + (wm + mt * 16 + l16) * 32 + rseg);
#pragma unroll
    for (int nt = 0; nt < 4; ++nt)
      bfr[nt] = *(const bf16x8*)(Bs + (wn + nt * 16 + l16) * 32 + rseg);

#pragma unroll
    for (int mt = 0; mt < 4; ++mt)
#pragma unroll
      for (int nt = 0; nt < 4; ++nt)
        acc[mt][nt] = __builtin_amdgcn_mfma_f32_16x16x32_bf16(
            af[mt], bfr[nt], acc[mt][nt], 0, 0, 0);

    __syncthreads();
  }

  // epilogue: C/D layout col=lane&15, row=quad*4+i  [verified m89/m91]
#pragma unroll
  for (int mt = 0; mt < 4; ++mt) {
    const size_t row0 = bm + wm + mt * 16 + quad * 4;
#pragma unroll
    for (int nt = 0; nt < 4; ++nt) {
      const size_t col = bn + wn + nt * 16 + l16;
      float* cp = C + row0 * N_DIM + col;
#pragma unroll
      for (int i = 0; i < 4; ++i)
        cp[(size_t)i * N_DIM] = acc[mt][nt][i];
    }
  }
}

// ------------------------------------------ fallback: fp32 tiled (insurance)
__global__ void gemm_f32_fallback(const float* __restrict__ A,
                                  const float* __restrict__ W,
                                  const float* __restrict__ Msk,
                                  float* __restrict__ C) {
  __shared__ float As[32][33];
  __shared__ float Bs[32][33];
  const int tx = threadIdx.x;
  const int ty = threadIdx.y;
  const size_t row0 = (size_t)blockIdx.y * 32;
  const size_t col0 = (size_t)blockIdx.x * 32;
  float acc[4] = {0.f, 0.f, 0.f, 0.f};
  for (int k0 = 0; k0 < K_DIM; k0 += 32) {
#pragma unroll
    for (int rr = 0; rr < 4; ++rr) {
      int rw = ty + rr * 8;
      As[rw][tx] = A[(row0 + rw) * K_DIM + k0 + tx];
      size_t gi = (size_t)(k0 + rw) * N_DIM + col0 + tx;
      Bs[rw][tx] = W[gi] * Msk[gi];
    }
    __syncthreads();
#pragma unroll
    for (int kk = 0; kk < 32; ++kk) {
      float b = Bs[kk][tx];
#pragma unroll
      for (int rr = 0; rr < 4; ++rr) acc[rr] += As[ty + rr * 8][kk] * b;
    }
    __syncthreads();
  }
#pragma unroll
  for (int rr = 0; rr < 4; ++rr)
    C[(row0 + ty + rr * 8) * N_DIM + col0 + tx] = acc[rr];
}

// ---------------------------------------------------------------- launcher
extern "C" void kernel_launch(void* const* d_in, const int* in_sizes, int n_in,
                              void* d_out, int out_size, void* d_ws,
                              size_t ws_size, hipStream_t stream) {
  const float* A   = (const float*)d_in[0];
  const float* W   = (const float*)d_in[1];
  const float* Msk = (const float*)d_in[2];
  float* C = (float*)d_out;

  const size_t bytesA = (size_t)M_DIM * K_DIM * sizeof(unsigned short);
  const size_t bytesB = (size_t)K_DIM * N_DIM * sizeof(unsigned short);

  if (ws_size >= bytesA + bytesB) {
    unsigned short* Abf = (unsigned short*)d_ws;
    unsigned short* Wt  = (unsigned short*)((char*)d_ws + bytesA);
    convert_a_kernel<<<dim3(((size_t)M_DIM * K_DIM) / 16 / 256), dim3(256), 0,
                       stream>>>(A, Abf);
    maskT_kernel<<<dim3(N_DIM / 64, K_DIM / 64), dim3(256), 0, stream>>>(
        W, Msk, Wt);
    gemm_bf16_kernel<<<dim3(N_DIM / 128, M_DIM / 128), dim3(256), 0, stream>>>(
        Abf, Wt, C);
  } else {
    gemm_f32_fallback<<<dim3(N_DIM / 32, M_DIM / 32), dim3(32, 8), 0,
                        stream>>>(A, W, Msk, C);
  }
}